// Round 3
// baseline (2140.117 us; speedup 1.0000x reference)
//
#include <hip/hip_runtime.h>
#include <math.h>

// Residual VQ: x (262144,128) fp32, codebooks (3,256,128) fp32.
// Output: [indices as float (262144*3)] ++ [quantized (262144*128)].
//
// ARITHMETIC CONTRACT (round 3, absmax=0 — do not change):
//   M_k  = OpenBLAS sgemm K-loop: sequential FMA chain j=0..127, acc init 0
//   A    = np.sum(r*r): pairwise_sum 8-accumulator scheme, products rounded
//          separately (fmaf(x,x,0) = single-rounded product, blocks fusion)
//   d2_k = (A - 2.0f*M_k) + B_k ; argmin strict < ascending k
//          (fmaf(-2,M,A)+B == (A-2.0f*M)+B bit-exact: 2*M exact, one rounding)
//   residual recompute: r = fmaf(-mask0,q0, x), then fmaf(-mask1,q1, ·)
//          == x - q0 - q1 bit-exact (sign-of-zero diffs unobservable)
//   quantized = (q0 + q1) + q2 elementwise fp32, ref order
//
// ROUND 7 CHANGE: round 6 fixed the spills (VGPR 56) but exposed the real
// bottleneck: FETCH_SIZE 3.1 GB = 24 re-sweeps of x (3 cb x 8 k-tiles x
// 134 MB); 128 KB/block x working set fits neither L1 nor L2 -> L3 at
// ~2 TB/s -> 1.7 ms. New split: block = 64 items (one per LANE), wave w
// owns entries [64w,64w+64) with 64 NAMED accumulators -> dim loop is the
// single outer loop, x read ONCE per codebook; block x set = 64x512B =
// 32 KB = L1, shared by all 4 waves and across codebooks. Argmin finished
// per-wave (strict <, ascending e) then combined across waves in ascending
// group order (== numpy first-min). gbase goes through readfirstlane so
// codebook addresses are provably wave-uniform -> s_load (scalar pipe),
// keeping VGPR ~115 (budget 168 via __launch_bounds__(256,3); no spill).

constexpr int kItems = 262144;
constexpr int kDim   = 128;
constexpr int kNcb   = 3;
constexpr int kK     = 256;
constexpr int kBlock = 256;
constexpr int kIPB   = 64;        // items per block (one per lane)
constexpr int kEPW   = 64;        // entries per wave
constexpr int NJC    = kDim / 8;  // 16 dim-chunks of 8

__device__ __forceinline__ float sq_rn(float x) {
    return __builtin_fmaf(x, x, 0.0f);
}

// numpy pairwise_sum, n=128: 8 accumulators, acc_j = v[j]+v[j+8]+...+v[j+120],
// combined ((r0+r1)+(r2+r3))+((r4+r5)+(r6+r7)). Used for the LDS B-table.
template <typename F>
__device__ __forceinline__ float np_pairwise128(F term) {
    float r0 = term(0), r1 = term(1), r2 = term(2), r3 = term(3),
          r4 = term(4), r5 = term(5), r6 = term(6), r7 = term(7);
    #pragma unroll
    for (int i = 8; i < 128; i += 8) {
        r0 = r0 + term(i + 0); r1 = r1 + term(i + 1);
        r2 = r2 + term(i + 2); r3 = r3 + term(i + 3);
        r4 = r4 + term(i + 4); r5 = r5 + term(i + 5);
        r6 = r6 + term(i + 6); r7 = r7 + term(i + 7);
    }
    return ((r0 + r1) + (r2 + r3)) + ((r4 + r5) + (r6 + r7));
}

#define X64(X) X(0) X(1) X(2) X(3) X(4) X(5) X(6) X(7) \
  X(8) X(9) X(10) X(11) X(12) X(13) X(14) X(15) \
  X(16) X(17) X(18) X(19) X(20) X(21) X(22) X(23) \
  X(24) X(25) X(26) X(27) X(28) X(29) X(30) X(31) \
  X(32) X(33) X(34) X(35) X(36) X(37) X(38) X(39) \
  X(40) X(41) X(42) X(43) X(44) X(45) X(46) X(47) \
  X(48) X(49) X(50) X(51) X(52) X(53) X(54) X(55) \
  X(56) X(57) X(58) X(59) X(60) X(61) X(62) X(63)

__global__ __launch_bounds__(kBlock, 3) void rvq_kernel(
    const float* __restrict__ x,
    const float* __restrict__ cb,
    float* __restrict__ out)
{
    // B_k = np.sum(cb*cb, axis=-1), bit-exact, staged in LDS
    __shared__ float s_B[kNcb * kK];
    __shared__ float s_bestv[kBlock];
    __shared__ int   s_besti[kBlock];

    for (int m = threadIdx.x; m < kNcb * kK; m += kBlock) {
        const float* row = cb + (size_t)m * kDim;
        s_B[m] = np_pairwise128([&](int j) { return sq_rn(row[j]); });
    }
    __syncthreads();

    // wave id must be PROVABLY uniform so codebook addrs become s_loads
    const int wav  = __builtin_amdgcn_readfirstlane((int)(threadIdx.x >> 6));
    const int lane = (int)(threadIdx.x & 63);
    const int item = blockIdx.x * kIPB + lane;
    const float4* xv = (const float4*)(x + (size_t)item * kDim);
    const int gbase = wav * kEPW;   // this wave's entry-group base

    int sel0 = 0, sel1 = 0, sel2 = 0;

    #pragma unroll 1
    for (int c = 0; c < kNcb; ++c) {
        const float* cbase = cb + (size_t)c * kK * kDim;
        const float* cbT   = cbase + (size_t)gbase * kDim;  // wave-uniform
        // previously selected codeword rows (per-lane gathers, L2-hot).
        // c==0: rows 0 (uniform) neutralized by mask0/mask1 = 0.
        const float4* w0v = (const float4*)(cb + (size_t)sel0 * kDim);
        const float4* w1v = (const float4*)(cb + (size_t)(kK + sel1) * kDim);
        const float mask0 = (c >= 1) ? 1.0f : 0.0f;
        const float mask1 = (c >= 2) ? 1.0f : 0.0f;

        #define MDECL(e) float m##e = 0.0f;
        X64(MDECL)
        #undef MDECL
        float a0 = 0.f, a1 = 0.f, a2 = 0.f, a3 = 0.f,
              a4 = 0.f, a5 = 0.f, a6 = 0.f, a7 = 0.f;

        #pragma unroll 1
        for (int jc = 0; jc < NJC; ++jc) {
            // residual chunk r[8jc .. 8jc+7], recomputed bit-exactly
            const float4 xa  = xv[2*jc],  xb  = xv[2*jc+1];
            const float4 wa0 = w0v[2*jc], wb0 = w0v[2*jc+1];
            const float4 wa1 = w1v[2*jc], wb1 = w1v[2*jc+1];
            float rr0 = __builtin_fmaf(-mask0, wa0.x, xa.x);
            float rr1 = __builtin_fmaf(-mask0, wa0.y, xa.y);
            float rr2 = __builtin_fmaf(-mask0, wa0.z, xa.z);
            float rr3 = __builtin_fmaf(-mask0, wa0.w, xa.w);
            float rr4 = __builtin_fmaf(-mask0, wb0.x, xb.x);
            float rr5 = __builtin_fmaf(-mask0, wb0.y, xb.y);
            float rr6 = __builtin_fmaf(-mask0, wb0.z, xb.z);
            float rr7 = __builtin_fmaf(-mask0, wb0.w, xb.w);
            rr0 = __builtin_fmaf(-mask1, wa1.x, rr0);
            rr1 = __builtin_fmaf(-mask1, wa1.y, rr1);
            rr2 = __builtin_fmaf(-mask1, wa1.z, rr2);
            rr3 = __builtin_fmaf(-mask1, wa1.w, rr3);
            rr4 = __builtin_fmaf(-mask1, wb1.x, rr4);
            rr5 = __builtin_fmaf(-mask1, wb1.y, rr5);
            rr6 = __builtin_fmaf(-mask1, wb1.z, rr6);
            rr7 = __builtin_fmaf(-mask1, wb1.w, rr7);

            // A accumulation: numpy 8-stripe scheme (single pass over dims)
            a0 = a0 + sq_rn(rr0); a1 = a1 + sq_rn(rr1);
            a2 = a2 + sq_rn(rr2); a3 = a3 + sq_rn(rr3);
            a4 = a4 + sq_rn(rr4); a5 = a5 + sq_rn(rr5);
            a6 = a6 + sq_rn(rr6); a7 = a7 + sq_rn(rr7);

            // 64 entries x 8 dims: resume each entry's sequential FMA chain
            #define MROW(e) { \
                const float4* rp = (const float4*)(cbT + (size_t)(e) * kDim); \
                const float4 ca = rp[2*jc], cd = rp[2*jc+1]; \
                m##e = __builtin_fmaf(rr0, ca.x, m##e); \
                m##e = __builtin_fmaf(rr1, ca.y, m##e); \
                m##e = __builtin_fmaf(rr2, ca.z, m##e); \
                m##e = __builtin_fmaf(rr3, ca.w, m##e); \
                m##e = __builtin_fmaf(rr4, cd.x, m##e); \
                m##e = __builtin_fmaf(rr5, cd.y, m##e); \
                m##e = __builtin_fmaf(rr6, cd.z, m##e); \
                m##e = __builtin_fmaf(rr7, cd.w, m##e); }
            X64(MROW)
            #undef MROW
        }

        const float A = ((a0 + a1) + (a2 + a3)) + ((a4 + a5) + (a6 + a7));

        // per-wave argmin over this wave's 64 entries (strict <, ascending)
        float best = INFINITY;
        int bi = gbase;
        #define EPI(e) { \
            float t = __builtin_fmaf(-2.0f, m##e, A) + s_B[c * kK + gbase + (e)]; \
            if (t < best) { best = t; bi = gbase + (e); } }
        X64(EPI)
        #undef EPI

        // cross-wave combine, ascending group order == numpy first-min
        s_bestv[threadIdx.x] = best;
        s_besti[threadIdx.x] = bi;
        __syncthreads();
        float bv = s_bestv[lane];
        int   bx = s_besti[lane];
        #pragma unroll
        for (int g = 1; g < kBlock / 64; ++g) {
            float v  = s_bestv[g * 64 + lane];
            int   ix = s_besti[g * 64 + lane];
            if (v < bv) { bv = v; bx = ix; }
        }
        if (c == 0) sel0 = bx; else if (c == 1) sel1 = bx; else sel2 = bx;
        __syncthreads();   // buffers reused next c
    }

    // --- outputs
    float* out_idx = out;                             // (items, 3) as float
    float* out_q   = out + (size_t)kItems * kNcb;     // (items, 128)
    if (wav == 0) {
        out_idx[(size_t)item * kNcb + 0] = (float)sel0;
        out_idx[(size_t)item * kNcb + 1] = (float)sel1;
        out_idx[(size_t)item * kNcb + 2] = (float)sel2;
    }
    // quantized: wave w writes dim-chunk [32w, 32w+32) of its lane's item
    const float4* q0v = (const float4*)(cb + ((size_t)0 * kK + sel0) * kDim);
    const float4* q1v = (const float4*)(cb + ((size_t)1 * kK + sel1) * kDim);
    const float4* q2v = (const float4*)(cb + ((size_t)2 * kK + sel2) * kDim);
    float4* qov = (float4*)(out_q + (size_t)item * kDim);
    #pragma unroll
    for (int i = 0; i < 8; ++i) {
        const int t = wav * 8 + i;
        const float4 u = q0v[t], v = q1v[t], w = q2v[t];
        float4 o;
        o.x = (u.x + v.x) + w.x;
        o.y = (u.y + v.y) + w.y;
        o.z = (u.z + v.z) + w.z;
        o.w = (u.w + v.w) + w.w;
        qov[t] = o;   // ((0+q0)+q1)+q2 in fp32, ref order
    }
}

extern "C" void kernel_launch(void* const* d_in, const int* in_sizes, int n_in,
                              void* d_out, int out_size, void* d_ws, size_t ws_size,
                              hipStream_t stream) {
    const float* x  = (const float*)d_in[0];
    const float* cb = (const float*)d_in[1];
    float* out = (float*)d_out;
    rvq_kernel<<<kItems / kIPB, kBlock, 0, stream>>>(x, cb, out);
}

// Round 4
// 1440.190 us; speedup vs baseline: 1.4860x; 1.4860x over previous
//
#include <hip/hip_runtime.h>
#include <math.h>

// Residual VQ: x (262144,128) fp32, codebooks (3,256,128) fp32.
// Output: [indices as float (262144*3)] ++ [quantized (262144*128)].
//
// ARITHMETIC CONTRACT (absmax=0 — do not change):
//   M_k  = OpenBLAS sgemm K-loop: sequential FMA chain j=0..127, acc init 0
//   A    = np.sum(r*r): pairwise_sum 8-accumulator scheme, products rounded
//          separately (fmaf(x,x,0) = single-rounded product, blocks fusion)
//   d2_k = (A - 2.0f*M_k) + B_k ; argmin strict < ascending k
//          (fmaf(-2,M,A)+B == (A-2.0f*M)+B bit-exact: 2*M exact, one rounding)
//   residual: r1 = x - q0 (1 rounding), r2 = r1 - q1 (1 rounding) — done as
//          in-place LDS subtract, elementwise fp32, ref order
//   quantized = (q0 + q1) + q2 elementwise fp32, ref order
//
// ROUND 8 CHANGE: round 7 fixed x-traffic (FETCH 3.1GB->100MB) but 64 named
// accumulators at VGPR_Count=68 meant the allocator parked them in AGPRs and
// shuffled (v_accvgpr_read/fma/write per FMA) -> VALU-busy 1420us = 4.3x the
// 327us FMA floor. Now: wave still owns 64 entries but sweeps them in 4
// sub-tiles of TE=16 accumulators (register-resident, no AGPR pressure).
// Residual r lives in LDS [64][132] fp32 (+4 pad: row bases hit all 8 bank
// quads -> ds_read_b128 at its 8-phase optimum), staged once from x
// (coalesced), updated in place per codebook (exact ref rounding). Per 8-dim
// chunk: 2 ds_read_b128 (24cyc) feed 128 FMA-instr (256cyc) = 9% overhead.
// Codebook operands via wave-uniform s_load (scalar pipe, proven r7). B-table
// computed once by a 768-thread pre-kernel into d_ws, consumed via uniform
// s_loads. Peak live VGPR ~55 -> allocator has no reason to touch AGPRs.

constexpr int kItems = 262144;
constexpr int kDim   = 128;
constexpr int kNcb   = 3;
constexpr int kK     = 256;
constexpr int kBlock = 256;
constexpr int kIPB   = 64;         // items per block (one per lane)
constexpr int kEPW   = 64;         // entries per wave
constexpr int TE     = 16;         // entries per sub-tile (named accumulators)
constexpr int NSUB   = kEPW / TE;  // 4
constexpr int NJC    = kDim / 8;   // 16 dim-chunks of 8
constexpr int RS     = 132;        // LDS residual row stride (floats), +4 pad

__device__ __forceinline__ float sq_rn(float x) {
    return __builtin_fmaf(x, x, 0.0f);
}

// numpy pairwise_sum, n=128: 8 accumulators, acc_j = v[j]+v[j+8]+...+v[j+120],
// combined ((r0+r1)+(r2+r3))+((r4+r5)+(r6+r7)).
template <typename F>
__device__ __forceinline__ float np_pairwise128(F term) {
    float r0 = term(0), r1 = term(1), r2 = term(2), r3 = term(3),
          r4 = term(4), r5 = term(5), r6 = term(6), r7 = term(7);
    #pragma unroll
    for (int i = 8; i < 128; i += 8) {
        r0 = r0 + term(i + 0); r1 = r1 + term(i + 1);
        r2 = r2 + term(i + 2); r3 = r3 + term(i + 3);
        r4 = r4 + term(i + 4); r5 = r5 + term(i + 5);
        r6 = r6 + term(i + 6); r7 = r7 + term(i + 7);
    }
    return ((r0 + r1) + (r2 + r3)) + ((r4 + r5) + (r6 + r7));
}

// ---------- pre-kernel: B_k = np.sum(cb*cb, axis=-1) into d_ws (768 floats)
__global__ void rvq_btable(const float* __restrict__ cb,
                           float* __restrict__ Bt)
{
    const int m = blockIdx.x * 256 + threadIdx.x;   // 3 blocks x 256 = 768
    const float* row = cb + (size_t)m * kDim;
    Bt[m] = np_pairwise128([&](int j) { return sq_rn(row[j]); });
}

#define X16(X) X(0) X(1) X(2) X(3) X(4) X(5) X(6) X(7) \
  X(8) X(9) X(10) X(11) X(12) X(13) X(14) X(15)

__global__ __launch_bounds__(kBlock, 4) void rvq_kernel(
    const float* __restrict__ x,
    const float* __restrict__ cb,
    const float* __restrict__ Bt,
    float* __restrict__ out)
{
    __shared__ float s_r[kIPB * RS];      // residuals, padded rows
    __shared__ float s_bestv[kBlock];
    __shared__ int   s_besti[kBlock];

    const int t = threadIdx.x;

    // ---- stage r = x (exact copy), coalesced global reads
    const float4* xb4 = (const float4*)(x + (size_t)blockIdx.x * kIPB * kDim);
    #pragma unroll
    for (int k = 0; k < (kIPB * kDim / 4) / kBlock; ++k) {   // 8 iters
        const int f = k * kBlock + t;              // float4 index in block tile
        const float4 v = xb4[f];
        *(float4*)(s_r + (f >> 5) * RS + (f & 31) * 4) = v;
    }
    __syncthreads();

    // wave id PROVABLY uniform so codebook addrs become s_loads
    const int wav  = __builtin_amdgcn_readfirstlane(t >> 6);
    const int lane = t & 63;
    const int item = blockIdx.x * kIPB + lane;
    const int gbase = wav * kEPW;
    const float* rrow = s_r + lane * RS;   // this lane's item row

    int sel0 = 0, sel1 = 0, sel2 = 0;

    #pragma unroll 1
    for (int c = 0; c < kNcb; ++c) {
        // ---- A = np.sum(r*r), numpy 8-stripe, from LDS (redundant per wave)
        float a0 = 0.f, a1 = 0.f, a2 = 0.f, a3 = 0.f,
              a4 = 0.f, a5 = 0.f, a6 = 0.f, a7 = 0.f;
        #pragma unroll
        for (int jc = 0; jc < NJC; ++jc) {
            const float4 ra = *(const float4*)(rrow + jc * 8);
            const float4 rb = *(const float4*)(rrow + jc * 8 + 4);
            a0 = a0 + sq_rn(ra.x); a1 = a1 + sq_rn(ra.y);
            a2 = a2 + sq_rn(ra.z); a3 = a3 + sq_rn(ra.w);
            a4 = a4 + sq_rn(rb.x); a5 = a5 + sq_rn(rb.y);
            a6 = a6 + sq_rn(rb.z); a7 = a7 + sq_rn(rb.w);
        }
        const float A = ((a0 + a1) + (a2 + a3)) + ((a4 + a5) + (a6 + a7));

        float best = INFINITY;
        int bi = gbase;

        #pragma unroll 1
        for (int sub = 0; sub < NSUB; ++sub) {
            const int kb = gbase + sub * TE;               // uniform
            const float* cbT = cb + ((size_t)c * kK + kb) * kDim;

            #define MDECL(e) float m##e = 0.0f;
            X16(MDECL)
            #undef MDECL

            #pragma unroll 2
            for (int jc = 0; jc < NJC; ++jc) {
                const float4 ra = *(const float4*)(rrow + jc * 8);
                const float4 rb = *(const float4*)(rrow + jc * 8 + 4);
                // 16 entries x 8 dims; per-entry chain stays sequential in j
                #define MROW(e) { \
                    const float* rp = cbT + (e) * kDim + jc * 8; \
                    m##e = __builtin_fmaf(ra.x, rp[0], m##e); \
                    m##e = __builtin_fmaf(ra.y, rp[1], m##e); \
                    m##e = __builtin_fmaf(ra.z, rp[2], m##e); \
                    m##e = __builtin_fmaf(ra.w, rp[3], m##e); \
                    m##e = __builtin_fmaf(rb.x, rp[4], m##e); \
                    m##e = __builtin_fmaf(rb.y, rp[5], m##e); \
                    m##e = __builtin_fmaf(rb.z, rp[6], m##e); \
                    m##e = __builtin_fmaf(rb.w, rp[7], m##e); }
                X16(MROW)
                #undef MROW
            }

            // epilogue for this sub-tile (ascending entries, strict <)
            #define EPI(e) { \
                float tt = __builtin_fmaf(-2.0f, m##e, A) + Bt[c * kK + kb + (e)]; \
                if (tt < best) { best = tt; bi = kb + (e); } }
            X16(EPI)
            #undef EPI
        }

        // ---- cross-wave argmin, ascending group order == numpy first-min
        s_bestv[t] = best;
        s_besti[t] = bi;
        __syncthreads();
        float bv = s_bestv[lane];
        int   bx = s_besti[lane];
        #pragma unroll
        for (int g = 1; g < kBlock / 64; ++g) {
            const float v  = s_bestv[g * 64 + lane];
            const int   ix = s_besti[g * 64 + lane];
            if (v < bv) { bv = v; bx = ix; }
        }
        if (c == 0) sel0 = bx; else if (c == 1) sel1 = bx; else sel2 = bx;

        // ---- in-place residual update (skip after last codebook)
        if (c < 2) {
            const int sel = (c == 0) ? sel0 : sel1;     // valid for item t&63
            const int it  = t & 63;
            const int qtr = t >> 6;
            const float4* cw4 =
                (const float4*)(cb + ((size_t)c * kK + sel) * kDim);
            #pragma unroll
            for (int i2 = 0; i2 < 8; ++i2) {
                const int c16 = qtr * 8 + i2;
                const float4 w = cw4[c16];
                float4 rv = *(float4*)(s_r + it * RS + c16 * 4);
                rv.x = rv.x - w.x;  rv.y = rv.y - w.y;   // one rounding each,
                rv.z = rv.z - w.z;  rv.w = rv.w - w.w;   // ref order
                *(float4*)(s_r + it * RS + c16 * 4) = rv;
            }
            __syncthreads();   // r ready for next c; also gates s_bestv reuse
        }
    }

    // ---- outputs
    float* out_idx = out;                             // (items, 3) as float
    float* out_q   = out + (size_t)kItems * kNcb;     // (items, 128)
    if (wav == 0) {
        out_idx[(size_t)item * kNcb + 0] = (float)sel0;
        out_idx[(size_t)item * kNcb + 1] = (float)sel1;
        out_idx[(size_t)item * kNcb + 2] = (float)sel2;
    }
    // quantized: thread t writes quarter (t>>6) of item (t&63)
    {
        const int it  = t & 63;
        const int qtr = t >> 6;
        const int oitem = blockIdx.x * kIPB + it;
        const float4* q0v = (const float4*)(cb + ((size_t)0 * kK + sel0) * kDim);
        const float4* q1v = (const float4*)(cb + ((size_t)1 * kK + sel1) * kDim);
        const float4* q2v = (const float4*)(cb + ((size_t)2 * kK + sel2) * kDim);
        float4* qov = (float4*)(out_q + (size_t)oitem * kDim);
        #pragma unroll
        for (int i2 = 0; i2 < 8; ++i2) {
            const int c16 = qtr * 8 + i2;
            const float4 u = q0v[c16], v = q1v[c16], w = q2v[c16];
            float4 o;
            o.x = (u.x + v.x) + w.x;
            o.y = (u.y + v.y) + w.y;
            o.z = (u.z + v.z) + w.z;
            o.w = (u.w + v.w) + w.w;
            qov[c16] = o;   // ((0+q0)+q1)+q2 in fp32, ref order
        }
    }
}

extern "C" void kernel_launch(void* const* d_in, const int* in_sizes, int n_in,
                              void* d_out, int out_size, void* d_ws, size_t ws_size,
                              hipStream_t stream) {
    const float* x  = (const float*)d_in[0];
    const float* cb = (const float*)d_in[1];
    float* out = (float*)d_out;
    float* Bt  = (float*)d_ws;     // 768 floats
    rvq_btable<<<kNcb, 256, 0, stream>>>(cb, Bt);
    rvq_kernel<<<kItems / kIPB, kBlock, 0, stream>>>(x, cb, Bt, out);
}